// Round 1
// baseline (402.749 us; speedup 1.0000x reference)
//
#include <hip/hip_runtime.h>

#define N_NODES 10000
#define N_EDGES 30000
#define ND 16      // node dim
#define ED 8       // edge dim
#define H 64       // hidden
#define BN 16      // bottleneck
#define NLAYERS 3
#define EPSN 1e-5f

#define TILE_E 64
#define NPB 32     // nodes per block in k_node1

// ---- degree ----
__global__ void k_deg(const int* __restrict__ dst, float* __restrict__ deg) {
    int e = blockIdx.x * 256 + threadIdx.x;
    if (e < N_EDGES) atomicAdd(&deg[dst[e]], 1.0f);
}

__global__ void k_inv(float* __restrict__ deg) {
    int n = blockIdx.x * 256 + threadIdx.x;
    if (n < N_NODES) {
        float d = deg[n];
        deg[n] = d > 0.f ? 1.f / d : 0.f;
    }
}

// ---- input MLP: h = relu(x @ w_in + b_in) ----
__global__ void k_in(const float* __restrict__ x, const float* __restrict__ w,
                     const float* __restrict__ b, float* __restrict__ h) {
    int idx = blockIdx.x * 256 + threadIdx.x;
    if (idx >= N_NODES * H) return;
    int n = idx >> 6, o = idx & 63;
    float s = b[o];
    #pragma unroll
    for (int d = 0; d < ND; ++d) s += x[n * ND + d] * w[d * H + o];
    h[idx] = fmaxf(s, 0.f);
}

// ---- fused edge kernel: t = relu(ea@ew1+eb1); msg = Z @ Wcat; scatter-atomic ----
__global__ __launch_bounds__(256) void k_msg(
    const float* __restrict__ h, const int* __restrict__ src, const int* __restrict__ dst,
    const float* __restrict__ ea, const float* __restrict__ ew1, const float* __restrict__ eb1,
    const float* __restrict__ ew2, const float* __restrict__ eb2, float* __restrict__ agg)
{
    __shared__ float h_lds[TILE_E][H + 1];   // padded: gather writes stride-65
    __shared__ float t_lds[TILE_E][BN];
    __shared__ float w_lds[64][H];           // one K-chunk of Wcat
    __shared__ int   s_src[TILE_E];
    __shared__ int   s_dst[TILE_E];

    const int tid = threadIdx.x;
    const int ebase = blockIdx.x * TILE_E;

    if (tid < TILE_E) {
        int e = ebase + tid;
        bool valid = e < N_EDGES;
        int ec = valid ? e : 0;
        s_src[tid] = src[ec];
        s_dst[tid] = valid ? dst[ec] : -1;
    }
    __syncthreads();

    // gather h_src rows (coalesced global reads, conflict-free LDS writes)
    #pragma unroll
    for (int p = 0; p < 16; ++p) {
        int el = p * 4 + (tid >> 6);
        int i = tid & 63;
        h_lds[el][i] = h[s_src[el] * H + i];
    }
    // t = relu(ea @ ew1 + eb1): 1024 values, 4 per thread
    #pragma unroll
    for (int j = 0; j < 4; ++j) {
        int idx = j * 256 + tid;
        int el = idx >> 4, b = idx & 15;
        int eg = min(ebase + el, N_EDGES - 1);
        float s = eb1[b];
        #pragma unroll
        for (int d = 0; d < ED; ++d) s += ea[eg * ED + d] * ew1[d * BN + b];
        t_lds[el][b] = fmaxf(s, 0.f);
    }

    float acc[4][4] = {};
    const int oq = (tid & 15) << 2;   // output col base
    const int eq = (tid >> 4) << 2;   // edge row base

    for (int b = 0; b < 17; ++b) {
        const float* wsrc = (b < 16) ? (ew2 + b * (H * H)) : eb2;
        __syncthreads();   // previous chunk fully consumed (also covers initial staging)
        #pragma unroll
        for (int j = 0; j < 4; ++j) {
            int i4 = j * 256 + tid;
            ((float4*)w_lds)[i4] = ((const float4*)wsrc)[i4];
        }
        __syncthreads();

        float pacc[4][4] = {};
        #pragma unroll 8
        for (int i = 0; i < 64; ++i) {
            float4 w = *(const float4*)&w_lds[i][oq];
            float h0 = h_lds[eq + 0][i];
            float h1 = h_lds[eq + 1][i];
            float h2 = h_lds[eq + 2][i];
            float h3 = h_lds[eq + 3][i];
            pacc[0][0] += h0 * w.x; pacc[0][1] += h0 * w.y; pacc[0][2] += h0 * w.z; pacc[0][3] += h0 * w.w;
            pacc[1][0] += h1 * w.x; pacc[1][1] += h1 * w.y; pacc[1][2] += h1 * w.z; pacc[1][3] += h1 * w.w;
            pacc[2][0] += h2 * w.x; pacc[2][1] += h2 * w.y; pacc[2][2] += h2 * w.z; pacc[2][3] += h2 * w.w;
            pacc[3][0] += h3 * w.x; pacc[3][1] += h3 * w.y; pacc[3][2] += h3 * w.z; pacc[3][3] += h3 * w.w;
        }
        #pragma unroll
        for (int ei = 0; ei < 4; ++ei) {
            float tb = (b < 16) ? t_lds[eq + ei][b] : 1.0f;
            #pragma unroll
            for (int oi = 0; oi < 4; ++oi) acc[ei][oi] += tb * pacc[ei][oi];
        }
    }

    // scatter-add into agg (mean scaling applied later via inv_deg)
    #pragma unroll
    for (int ei = 0; ei < 4; ++ei) {
        int d = s_dst[eq + ei];
        if (d < 0) continue;
        #pragma unroll
        for (int oi = 0; oi < 4; ++oi)
            atomicAdd(&agg[d * H + oq + oi], acc[ei][oi]);
    }
}

// ---- node kernel 1: out = inv_deg*agg + h@w_root + bias; accumulate sum/sumsq ----
__global__ __launch_bounds__(256) void k_node1(
    const float* __restrict__ agg, const float* __restrict__ invd, const float* __restrict__ h,
    const float* __restrict__ wroot, const float* __restrict__ cb,
    float* __restrict__ out, float* __restrict__ sums)
{
    __shared__ float w_lds[64][H];
    __shared__ float red[2][4][64];
    const int tid = threadIdx.x;
    #pragma unroll
    for (int j = 0; j < 4; ++j)
        ((float4*)w_lds)[j * 256 + tid] = ((const float4*)wroot)[j * 256 + tid];
    __syncthreads();

    const int o = tid & 63, g = tid >> 6;
    const int nbase = blockIdx.x * NPB;
    float ls = 0.f, lq = 0.f;
    for (int j = 0; j < NPB / 4; ++j) {
        int n = nbase + j * 4 + g;
        if (n < N_NODES) {
            float s = cb[o] + invd[n] * agg[n * H + o];
            #pragma unroll
            for (int i = 0; i < H; ++i) s += h[n * H + i] * w_lds[i][o];
            out[n * H + o] = s;
            ls += s;
            lq += s * s;
        }
    }
    red[0][g][o] = ls;
    red[1][g][o] = lq;
    __syncthreads();
    if (tid < 64) {
        float a = red[0][0][tid] + red[0][1][tid] + red[0][2][tid] + red[0][3][tid];
        atomicAdd(&sums[tid], a);
    } else if (tid < 128) {
        int oo = tid - 64;
        float a = red[1][0][oo] + red[1][1][oo] + red[1][2][oo] + red[1][3][oo];
        atomicAdd(&sums[64 + oo], a);
    }
}

// ---- node kernel 2: BN (batch stats) + ReLU + residual ----
__global__ void k_node2(const float* __restrict__ out, const float* __restrict__ sums,
                        const float* __restrict__ gamma, const float* __restrict__ beta,
                        const float* __restrict__ hin, float* __restrict__ hout)
{
    int idx = blockIdx.x * 256 + threadIdx.x;
    if (idx >= N_NODES * H) return;
    int o = idx & 63;
    const float invN = 1.0f / (float)N_NODES;
    float mu = sums[o] * invN;
    float var = sums[64 + o] * invN - mu * mu;
    float scale = gamma[o] * rsqrtf(var + EPSN);
    float v = (out[idx] - mu) * scale + beta[o];
    hout[idx] = fmaxf(v, 0.f) + hin[idx];
}

extern "C" void kernel_launch(void* const* d_in, const int* in_sizes, int n_in,
                              void* d_out, int out_size, void* d_ws, size_t ws_size,
                              hipStream_t stream) {
    const float* x     = (const float*)d_in[0];
    const int*   ei    = (const int*)  d_in[1];
    const float* ea    = (const float*)d_in[2];
    const float* w_in  = (const float*)d_in[3];
    const float* b_in  = (const float*)d_in[4];
    const float* ew1   = (const float*)d_in[5];   // [3,8,16]
    const float* eb1   = (const float*)d_in[6];   // [3,16]
    const float* ew2   = (const float*)d_in[7];   // [3,16,4096]
    const float* eb2   = (const float*)d_in[8];   // [3,4096]
    const float* wroot = (const float*)d_in[9];   // [3,64,64]
    const float* cb    = (const float*)d_in[10];  // [3,64]
    const float* gamma = (const float*)d_in[11];  // [3,64]
    const float* beta  = (const float*)d_in[12];  // [3,64]
    float* outp = (float*)d_out;

    float* ws   = (float*)d_ws;
    float* invd = ws;                      // N
    float* h    = invd + N_NODES;          // N*H
    float* agg  = h + N_NODES * H;         // N*H   (contiguous with sums for one memset)
    float* sums = agg + N_NODES * H;       // 128
    float* outb = sums + 128;              // N*H

    const int* srcp = ei;
    const int* dstp = ei + N_EDGES;

    hipMemsetAsync(invd, 0, N_NODES * sizeof(float), stream);
    k_deg<<<(N_EDGES + 255) / 256, 256, 0, stream>>>(dstp, invd);
    k_inv<<<(N_NODES + 255) / 256, 256, 0, stream>>>(invd);
    k_in<<<(N_NODES * H + 255) / 256, 256, 0, stream>>>(x, w_in, b_in, h);

    for (int l = 0; l < NLAYERS; ++l) {
        hipMemsetAsync(agg, 0, (N_NODES * H + 128) * sizeof(float), stream);
        k_msg<<<(N_EDGES + TILE_E - 1) / TILE_E, 256, 0, stream>>>(
            h, srcp, dstp, ea,
            ew1 + l * ED * BN, eb1 + l * BN,
            ew2 + l * BN * H * H, eb2 + l * H * H, agg);
        k_node1<<<(N_NODES + NPB - 1) / NPB, 256, 0, stream>>>(
            agg, invd, h, wroot + l * H * H, cb + l * H, outb, sums);
        float* hout = (l == NLAYERS - 1) ? outp : h;
        k_node2<<<(N_NODES * H + 255) / 256, 256, 0, stream>>>(
            outb, sums, gamma + l * H, beta + l * H, h, hout);
    }
}

// Round 2
// 289.545 us; speedup vs baseline: 1.3910x; 1.3910x over previous
//
#include <hip/hip_runtime.h>
#include <hip/hip_bf16.h>

#define N_NODES 10000
#define N_EDGES 30000
#define ND 16      // node dim
#define ED 8       // edge dim
#define H 64       // hidden
#define BNECK 16   // bottleneck
#define NLAYERS 3
#define EPSN 1e-5f

#define NPB 32     // nodes per block in k_node1
#define NCHUNK 17  // 16 ew2 chunks + 1 eb2 bias chunk
#define WF_PER_LAYER (NCHUNK * 4096)   // 69632 bf16 elements per layer

typedef __attribute__((ext_vector_type(8))) short short8;
typedef __attribute__((ext_vector_type(4))) float f32x4;

static __device__ __forceinline__ short f2bf(float f) {
    __hip_bfloat16 b = __float2bfloat16(f);
    return __builtin_bit_cast(short, b);
}

// ---- degree ----
__global__ void k_deg(const int* __restrict__ dst, float* __restrict__ deg) {
    int e = blockIdx.x * 256 + threadIdx.x;
    if (e < N_EDGES) atomicAdd(&deg[dst[e]], 1.0f);
}

__global__ void k_inv(float* __restrict__ deg) {
    int n = blockIdx.x * 256 + threadIdx.x;
    if (n < N_NODES) {
        float d = deg[n];
        deg[n] = d > 0.f ? 1.f / d : 0.f;
    }
}

// ---- input MLP: h = relu(x @ w_in + b_in) ----
__global__ void k_in(const float* __restrict__ x, const float* __restrict__ w,
                     const float* __restrict__ b, float* __restrict__ h) {
    int idx = blockIdx.x * 256 + threadIdx.x;
    if (idx >= N_NODES * H) return;
    int n = idx >> 6, o = idx & 63;
    float s = b[o];
    #pragma unroll
    for (int d = 0; d < ND; ++d) s += x[n * ND + d] * w[d * H + o];
    h[idx] = fmaxf(s, 0.f);
}

// ---- W prep: ew2|eb2 -> fragment-ordered bf16 for 16x16x32 MFMA B-operand ----
// Per layer, per 64-k chunk c, the chunk block is 4096 bf16 laid out as
// [kstep s(2)][coltile ct(4)][lane(64)][j(8)], where lane's element j holds
// Wcat[k][o] with k = c*64 + s*32 + (lane>>4)*8 + j, o = ct*16 + (lane&15).
__global__ void k_wprep(const float* __restrict__ ew2, const float* __restrict__ eb2,
                        ushort* __restrict__ wf) {
    int idx = blockIdx.x * 256 + threadIdx.x;
    if (idx >= NLAYERS * WF_PER_LAYER) return;
    int l = idx / WF_PER_LAYER;
    int r = idx % WF_PER_LAYER;
    int c = r >> 12;
    int q = r & 4095;
    int j    = q & 7;
    int lane = (q >> 3) & 63;
    int ct   = (q >> 9) & 3;
    int s    = q >> 11;
    int k = c * 64 + s * 32 + ((lane >> 4) * 8) + j;
    int o = ct * 16 + (lane & 15);
    float v;
    if (k < 1024) v = ew2[l * 65536 + k * 64 + o];
    else          v = eb2[l * 4096 + (k - 1024) * 64 + o];
    wf[idx] = __builtin_bit_cast(ushort, __float2bfloat16(v));
}

// ---- fused edge kernel (MFMA): msg = Z @ Wcat, Z[e, b*64+i] = t[e,b]*h_src[e,i] ----
// Block: 128 threads = 2 waves; each wave owns 32 edges (2 A-stripes of 16).
__global__ __launch_bounds__(128) void k_msg(
    const float* __restrict__ h, const int* __restrict__ src, const int* __restrict__ dst,
    const float* __restrict__ ea, const float* __restrict__ ew1, const float* __restrict__ eb1,
    const ushort* __restrict__ wf, float* __restrict__ agg)
{
    __shared__ float h_lds[64 * 64];   // [edge][16B-swizzled cols]
    __shared__ float t_lds[64][17];    // 16 bneck + 1.0 for bias chunk
    __shared__ int s_src[64], s_dst[64];

    const int tid = threadIdx.x;
    const int ebase = blockIdx.x * 64;

    if (tid < 64) {
        int e = ebase + tid;
        bool v = e < N_EDGES;
        s_src[tid] = src[v ? e : 0];
        s_dst[tid] = v ? dst[e] : -1;
    }
    __syncthreads();

    // gather h_src rows; XOR-swizzle 16B blocks: col4' = col4 ^ (edge&15)
    #pragma unroll
    for (int p = 0; p < 8; ++p) {
        int el = p * 8 + (tid >> 4);
        int c4 = tid & 15;
        f32x4 v = *(const f32x4*)&h[s_src[el] * H + c4 * 4];
        *(f32x4*)&h_lds[el * 64 + ((c4 ^ (el & 15)) << 2)] = v;
    }
    // t = relu(ea @ ew1 + eb1): 64 edges x 16, 8 per thread
    {
        int el = tid >> 1, bg = (tid & 1) * 8;
        int eg = min(ebase + el, N_EDGES - 1);
        float av[8];
        *(f32x4*)&av[0] = *(const f32x4*)&ea[eg * ED];
        *(f32x4*)&av[4] = *(const f32x4*)&ea[eg * ED + 4];
        #pragma unroll
        for (int b = 0; b < 8; ++b) {
            float s = eb1[bg + b];
            #pragma unroll
            for (int d = 0; d < ED; ++d) s += av[d] * ew1[d * BNECK + bg + b];
            t_lds[el][bg + b] = fmaxf(s, 0.f);
        }
    }
    if (tid < 64) t_lds[tid][16] = 1.0f;
    __syncthreads();

    const int lane = tid & 63;
    const int wv = tid >> 6;
    const int l15 = lane & 15;
    const int lk8 = (lane >> 4) * 8;   // k offset within 32-step
    const int er0 = wv * 32 + l15;     // stripe-0 A row (edge)
    const int er1 = er0 + 16;          // stripe-1

    f32x4 acc[2][4];
    #pragma unroll
    for (int i = 0; i < 2; ++i)
        #pragma unroll
        for (int j = 0; j < 4; ++j) acc[i][j] = (f32x4){0.f, 0.f, 0.f, 0.f};

    for (int c = 0; c < NCHUNK; ++c) {
        const float t0 = t_lds[er0][c];
        const float t1 = t_lds[er1][c];
        #pragma unroll
        for (int s = 0; s < 2; ++s) {
            const int c40 = (s * 32 + lk8) >> 2;
            short8 a0, a1;
            {
                const f32x4 x = *(const f32x4*)&h_lds[er0 * 64 + ((c40 ^ l15) << 2)];
                const f32x4 y = *(const f32x4*)&h_lds[er0 * 64 + (((c40 + 1) ^ l15) << 2)];
                a0[0] = f2bf(x[0] * t0); a0[1] = f2bf(x[1] * t0);
                a0[2] = f2bf(x[2] * t0); a0[3] = f2bf(x[3] * t0);
                a0[4] = f2bf(y[0] * t0); a0[5] = f2bf(y[1] * t0);
                a0[6] = f2bf(y[2] * t0); a0[7] = f2bf(y[3] * t0);
            }
            {
                const f32x4 x = *(const f32x4*)&h_lds[er1 * 64 + ((c40 ^ l15) << 2)];
                const f32x4 y = *(const f32x4*)&h_lds[er1 * 64 + (((c40 + 1) ^ l15) << 2)];
                a1[0] = f2bf(x[0] * t1); a1[1] = f2bf(x[1] * t1);
                a1[2] = f2bf(x[2] * t1); a1[3] = f2bf(x[3] * t1);
                a1[4] = f2bf(y[0] * t1); a1[5] = f2bf(y[1] * t1);
                a1[6] = f2bf(y[2] * t1); a1[7] = f2bf(y[3] * t1);
            }
            // B-frags: coalesced 16B loads from frag-ordered W (L2-resident)
            const ushort* bp = wf + (size_t)(((c * 2 + s) * 4) * 64 + lane) * 8;
            #pragma unroll
            for (int ct = 0; ct < 4; ++ct) {
                short8 bfrag = *(const short8*)(bp + ct * 512);
                acc[0][ct] = __builtin_amdgcn_mfma_f32_16x16x32_bf16(a0, bfrag, acc[0][ct], 0, 0, 0);
                acc[1][ct] = __builtin_amdgcn_mfma_f32_16x16x32_bf16(a1, bfrag, acc[1][ct], 0, 0, 0);
            }
        }
    }

    // scatter: D layout col = lane&15, row = (lane>>4)*4 + reg
    #pragma unroll
    for (int st = 0; st < 2; ++st) {
        const int rb = wv * 32 + st * 16 + (lane >> 4) * 4;
        #pragma unroll
        for (int r = 0; r < 4; ++r) {
            int d = s_dst[rb + r];
            if (d >= 0) {
                #pragma unroll
                for (int ct = 0; ct < 4; ++ct)
                    atomicAdd(&agg[d * H + ct * 16 + l15], acc[st][ct][r]);
            }
        }
    }
}

// ---- node kernel 1: out = inv_deg*agg + h@w_root + bias; accumulate sum/sumsq ----
__global__ __launch_bounds__(256) void k_node1(
    const float* __restrict__ agg, const float* __restrict__ invd, const float* __restrict__ h,
    const float* __restrict__ wroot, const float* __restrict__ cb,
    float* __restrict__ out, float* __restrict__ sums)
{
    __shared__ float w_lds[64][H];
    __shared__ float red[2][4][64];
    const int tid = threadIdx.x;
    #pragma unroll
    for (int j = 0; j < 4; ++j)
        ((float4*)w_lds)[j * 256 + tid] = ((const float4*)wroot)[j * 256 + tid];
    __syncthreads();

    const int o = tid & 63, g = tid >> 6;
    const int nbase = blockIdx.x * NPB;
    float ls = 0.f, lq = 0.f;
    for (int j = 0; j < NPB / 4; ++j) {
        int n = nbase + j * 4 + g;
        if (n < N_NODES) {
            float s = cb[o] + invd[n] * agg[n * H + o];
            #pragma unroll
            for (int i = 0; i < H; ++i) s += h[n * H + i] * w_lds[i][o];
            out[n * H + o] = s;
            ls += s;
            lq += s * s;
        }
    }
    red[0][g][o] = ls;
    red[1][g][o] = lq;
    __syncthreads();
    if (tid < 64) {
        float a = red[0][0][tid] + red[0][1][tid] + red[0][2][tid] + red[0][3][tid];
        atomicAdd(&sums[tid], a);
    } else if (tid < 128) {
        int oo = tid - 64;
        float a = red[1][0][oo] + red[1][1][oo] + red[1][2][oo] + red[1][3][oo];
        atomicAdd(&sums[64 + oo], a);
    }
}

// ---- node kernel 2: BN (batch stats) + ReLU + residual ----
__global__ void k_node2(const float* __restrict__ out, const float* __restrict__ sums,
                        const float* __restrict__ gamma, const float* __restrict__ beta,
                        const float* __restrict__ hin, float* __restrict__ hout)
{
    int idx = blockIdx.x * 256 + threadIdx.x;
    if (idx >= N_NODES * H) return;
    int o = idx & 63;
    const float invN = 1.0f / (float)N_NODES;
    float mu = sums[o] * invN;
    float var = sums[64 + o] * invN - mu * mu;
    float scale = gamma[o] * rsqrtf(var + EPSN);
    float v = (out[idx] - mu) * scale + beta[o];
    hout[idx] = fmaxf(v, 0.f) + hin[idx];
}

extern "C" void kernel_launch(void* const* d_in, const int* in_sizes, int n_in,
                              void* d_out, int out_size, void* d_ws, size_t ws_size,
                              hipStream_t stream) {
    const float* x     = (const float*)d_in[0];
    const int*   ei    = (const int*)  d_in[1];
    const float* ea    = (const float*)d_in[2];
    const float* w_in  = (const float*)d_in[3];
    const float* b_in  = (const float*)d_in[4];
    const float* ew1   = (const float*)d_in[5];   // [3,8,16]
    const float* eb1   = (const float*)d_in[6];   // [3,16]
    const float* ew2   = (const float*)d_in[7];   // [3,16,4096]
    const float* eb2   = (const float*)d_in[8];   // [3,4096]
    const float* wroot = (const float*)d_in[9];   // [3,64,64]
    const float* cb    = (const float*)d_in[10];  // [3,64]
    const float* gamma = (const float*)d_in[11];  // [3,64]
    const float* beta  = (const float*)d_in[12];  // [3,64]
    float* outp = (float*)d_out;

    float* ws   = (float*)d_ws;
    float* invd = ws;                      // N
    float* h    = invd + N_NODES;          // N*H
    float* agg  = h + N_NODES * H;         // N*H (contiguous with sums: one memset)
    float* sums = agg + N_NODES * H;       // 128
    float* outb = sums + 128;              // N*H
    ushort* wfg = (ushort*)(outb + N_NODES * H);  // 3*69632 bf16 (16B-aligned)

    const int* srcp = ei;
    const int* dstp = ei + N_EDGES;

    hipMemsetAsync(invd, 0, N_NODES * sizeof(float), stream);
    k_deg<<<(N_EDGES + 255) / 256, 256, 0, stream>>>(dstp, invd);
    k_inv<<<(N_NODES + 255) / 256, 256, 0, stream>>>(invd);
    k_in<<<(N_NODES * H + 255) / 256, 256, 0, stream>>>(x, w_in, b_in, h);
    k_wprep<<<(NLAYERS * WF_PER_LAYER + 255) / 256, 256, 0, stream>>>(ew2, eb2, wfg);

    for (int l = 0; l < NLAYERS; ++l) {
        hipMemsetAsync(agg, 0, (N_NODES * H + 128) * sizeof(float), stream);
        k_msg<<<(N_EDGES + 63) / 64, 128, 0, stream>>>(
            h, srcp, dstp, ea,
            ew1 + l * ED * BNECK, eb1 + l * BNECK,
            wfg + (size_t)l * WF_PER_LAYER, agg);
        k_node1<<<(N_NODES + NPB - 1) / NPB, 256, 0, stream>>>(
            agg, invd, h, wroot + l * H * H, cb + l * H, outb, sums);
        float* hout = (l == NLAYERS - 1) ? outp : h;
        k_node2<<<(N_NODES * H + 255) / 256, 256, 0, stream>>>(
            outb, sums, gamma + l * H, beta + l * H, h, hout);
    }
}